// Round 4
// baseline (65.599 us; speedup 1.0000x reference)
//
#include <hip/hip_runtime.h>
#include <math.h>

// MultiTaskLoss: fused single-pass reduction over B=4M samples.
// R3: R0 scalar-load body + non-temporal (nt) loads on the 128MB logits
// stream via ext_vector_type (builtin rejects HIP_vector_type). Goal:
// keep the other 176MB Infinity-Cache resident across graph replays.

constexpr int GRID  = 2048;
constexpr int BLOCK = 256;
constexpr float RADF = 0.017453292519943295f;  // pi/180

typedef float floatx4 __attribute__((ext_vector_type(4)));

__device__ __forceinline__ floatx4 ntload4(const floatx4* p) {
    return __builtin_nontemporal_load(p);
}

__global__ void __launch_bounds__(BLOCK) mtl_partials(
    const float2* __restrict__ pred_gps,
    const float*  __restrict__ true_lat,
    const float*  __restrict__ true_lon,
    const float2* __restrict__ pred_time,
    const float*  __restrict__ hour,
    const float*  __restrict__ minute,
    const floatx4* __restrict__ logits4,   // 2 floatx4 per sample (nt)
    const int*    __restrict__ orient,
    const float*  __restrict__ pred_alt,
    const float*  __restrict__ alt,
    const float*  __restrict__ gps_scale,
    const float*  __restrict__ gps_offset,
    double*       __restrict__ partials,   // [4][GRID]
    int B)
{
    const float s0 = gps_scale[0],  s1 = gps_scale[1];
    const float o0 = gps_offset[0], o1 = gps_offset[1];

    float ag = 0.f, at = 0.f, ao = 0.f, aa = 0.f;

    int tid    = blockIdx.x * blockDim.x + threadIdx.x;
    int stride = gridDim.x * blockDim.x;

    for (int i = tid; i < B; i += stride) {
        // ---- GPS haversine ----
        float2 pg = pred_gps[i];
        float plat = fmaf(pg.x, s0, o0) * RADF;
        float plon = fmaf(pg.y, s1, o1) * RADF;
        float tlat = fmaf(true_lat[i], s0, o0) * RADF;
        float tlon = fmaf(true_lon[i], s1, o1) * RADF;
        float sdla = __sinf(0.5f * (plat - tlat));
        float sdlo = __sinf(0.5f * (plon - tlon));
        float a = sdla * sdla + __cosf(tlat) * __cosf(plat) * (sdlo * sdlo);
        a = fminf(fmaxf(a, 0.f), 1.f);
        ag += 6371.0f * (2.0f * asinf(sqrtf(a)));

        // ---- time MSE ----
        float2 pt = pred_time[i];
        float dh = pt.x - hour[i];
        float dm = pt.y - minute[i];
        at += dh * dh + dm * dm;

        // ---- orientation NLL: lse(logits) - logits[k]  (nt loads) ----
        floatx4 l0 = ntload4(&logits4[2 * i]);
        floatx4 l1 = ntload4(&logits4[2 * i + 1]);
        float m = fmaxf(fmaxf(fmaxf(l0.x, l0.y), fmaxf(l0.z, l0.w)),
                        fmaxf(fmaxf(l1.x, l1.y), fmaxf(l1.z, l1.w)));
        float se = __expf(l0.x - m) + __expf(l0.y - m) +
                   __expf(l0.z - m) + __expf(l0.w - m) +
                   __expf(l1.x - m) + __expf(l1.y - m) +
                   __expf(l1.z - m) + __expf(l1.w - m);
        float lse = m + __logf(se);
        int k = orient[i];
        float lk = (k < 4)
            ? ((k == 0) ? l0.x : (k == 1) ? l0.y : (k == 2) ? l0.z : l0.w)
            : ((k == 4) ? l1.x : (k == 5) ? l1.y : (k == 6) ? l1.z : l1.w);
        ao += lse - lk;

        // ---- altitude MSE ----
        float da = pred_alt[i] - alt[i];
        aa += da * da;
    }

    // ---- wave reduce (64 lanes) ----
    #pragma unroll
    for (int off = 32; off > 0; off >>= 1) {
        ag += __shfl_down(ag, off, 64);
        at += __shfl_down(at, off, 64);
        ao += __shfl_down(ao, off, 64);
        aa += __shfl_down(aa, off, 64);
    }

    __shared__ double sm[4][4];  // [wave][loss]
    int lane = threadIdx.x & 63;
    int wave = threadIdx.x >> 6;
    if (lane == 0) {
        sm[wave][0] = (double)ag;
        sm[wave][1] = (double)at;
        sm[wave][2] = (double)ao;
        sm[wave][3] = (double)aa;
    }
    __syncthreads();
    if (threadIdx.x < 4) {
        double s = sm[0][threadIdx.x] + sm[1][threadIdx.x] +
                   sm[2][threadIdx.x] + sm[3][threadIdx.x];
        partials[threadIdx.x * gridDim.x + blockIdx.x] = s;
    }
}

__global__ void __launch_bounds__(256) mtl_final(
    const double* __restrict__ partials,  // [4][GRID]
    float* __restrict__ out, int G, int B)
{
    int t = threadIdx.x;
    double v[4];
    #pragma unroll
    for (int k = 0; k < 4; ++k) {
        double s = 0.0;
        for (int b = t; b < G; b += 256) s += partials[k * G + b];
        v[k] = s;
    }
    #pragma unroll
    for (int off = 32; off > 0; off >>= 1) {
        #pragma unroll
        for (int k = 0; k < 4; ++k) v[k] += __shfl_down(v[k], off, 64);
    }
    __shared__ double sm[4][4];
    int lane = t & 63, wave = t >> 6;
    if (lane == 0) {
        #pragma unroll
        for (int k = 0; k < 4; ++k) sm[wave][k] = v[k];
    }
    __syncthreads();
    if (t == 0) {
        double g = 0, tm = 0, od = 0, al = 0;
        #pragma unroll
        for (int w = 0; w < 4; ++w) {
            g += sm[w][0]; tm += sm[w][1]; od += sm[w][2]; al += sm[w][3];
        }
        double gps    = g  / (double)B;
        double timeL  = tm / (2.0 * (double)B);
        double orient = od / (double)B;
        double altL   = al / (double)B;
        double total  = gps + 0.5 * timeL + 0.3 * orient + 0.2 * altL;
        out[0] = (float)total;
        out[1] = (float)gps;
        out[2] = (float)timeL;
        out[3] = (float)orient;
        out[4] = (float)altL;
    }
}

extern "C" void kernel_launch(void* const* d_in, const int* in_sizes, int n_in,
                              void* d_out, int out_size, void* d_ws, size_t ws_size,
                              hipStream_t stream) {
    const float2* pred_gps   = (const float2*)d_in[0];
    const float*  true_lat   = (const float*)d_in[1];
    const float*  true_lon   = (const float*)d_in[2];
    const float2* pred_time  = (const float2*)d_in[3];
    const float*  hour       = (const float*)d_in[4];
    const float*  minute     = (const float*)d_in[5];
    const floatx4* logits4   = (const floatx4*)d_in[6];
    const int*    orient     = (const int*)d_in[7];
    const float*  pred_alt   = (const float*)d_in[8];
    const float*  alt        = (const float*)d_in[9];
    const float*  gps_scale  = (const float*)d_in[10];
    const float*  gps_offset = (const float*)d_in[11];

    int B = in_sizes[1];  // true_lat element count
    double* partials = (double*)d_ws;  // 4*GRID*8 = 64 KiB

    mtl_partials<<<GRID, BLOCK, 0, stream>>>(
        pred_gps, true_lat, true_lon, pred_time, hour, minute,
        logits4, orient, pred_alt, alt, gps_scale, gps_offset,
        partials, B);
    mtl_final<<<1, 256, 0, stream>>>(partials, (float*)d_out, GRID, B);
}

// Round 5
// 61.418 us; speedup vs baseline: 1.0681x; 1.0681x over previous
//
#include <hip/hip_runtime.h>
#include <math.h>

// MultiTaskLoss: fused single-pass reduction over B=4M samples.
// R4: 2-sample-per-thread unroll with all loads clustered at loop top
// (13 VMEM ops in flight per thread) to raise per-wave MLP. No nt
// (R3 falsified the MALL-bypass theory). GRID=2048 fills all wave slots.

constexpr int GRID  = 2048;
constexpr int BLOCK = 256;
constexpr float RADF = 0.017453292519943295f;  // pi/180

__device__ __forceinline__ void do_sample(
    float pgx, float pgy, float tla_, float tlo_,
    float ptx, float pty, float h, float mn,
    const float4& l0, const float4& l1, int k,
    float pa, float al,
    float s0, float s1, float o0, float o1,
    float& ag, float& at, float& ao, float& aa)
{
    // ---- GPS haversine ----
    float plat = fmaf(pgx, s0, o0) * RADF;
    float plon = fmaf(pgy, s1, o1) * RADF;
    float tlat = fmaf(tla_, s0, o0) * RADF;
    float tlon = fmaf(tlo_, s1, o1) * RADF;
    float sdla = __sinf(0.5f * (plat - tlat));
    float sdlo = __sinf(0.5f * (plon - tlon));
    float a = sdla * sdla + __cosf(tlat) * __cosf(plat) * (sdlo * sdlo);
    a = fminf(fmaxf(a, 0.f), 1.f);
    ag += 6371.0f * (2.0f * asinf(sqrtf(a)));

    // ---- time MSE ----
    float dh = ptx - h;
    float dm = pty - mn;
    at += dh * dh + dm * dm;

    // ---- orientation NLL ----
    float m = fmaxf(fmaxf(fmaxf(l0.x, l0.y), fmaxf(l0.z, l0.w)),
                    fmaxf(fmaxf(l1.x, l1.y), fmaxf(l1.z, l1.w)));
    float se = __expf(l0.x - m) + __expf(l0.y - m) +
               __expf(l0.z - m) + __expf(l0.w - m) +
               __expf(l1.x - m) + __expf(l1.y - m) +
               __expf(l1.z - m) + __expf(l1.w - m);
    float lse = m + __logf(se);
    float lk = (k < 4)
        ? ((k == 0) ? l0.x : (k == 1) ? l0.y : (k == 2) ? l0.z : l0.w)
        : ((k == 4) ? l1.x : (k == 5) ? l1.y : (k == 6) ? l1.z : l1.w);
    ao += lse - lk;

    // ---- altitude MSE ----
    float da = pa - al;
    aa += da * da;
}

__global__ void __launch_bounds__(BLOCK) mtl_partials(
    const float4* __restrict__ pred_gps4,   // [B/2] : 2 samples per elem
    const float2* __restrict__ true_lat2,   // [B/2]
    const float2* __restrict__ true_lon2,
    const float4* __restrict__ pred_time4,  // [B/2]
    const float2* __restrict__ hour2,
    const float2* __restrict__ minute2,
    const float4* __restrict__ logits4,     // [B*2] : 4 per 2 samples
    const int2*   __restrict__ orient2,
    const float2* __restrict__ pred_alt2,
    const float2* __restrict__ alt2,
    const float*  __restrict__ gps_scale,
    const float*  __restrict__ gps_offset,
    double*       __restrict__ partials,    // [4][GRID]
    int B)
{
    const float s0 = gps_scale[0],  s1 = gps_scale[1];
    const float o0 = gps_offset[0], o1 = gps_offset[1];

    float ag = 0.f, at = 0.f, ao = 0.f, aa = 0.f;

    int tid    = blockIdx.x * blockDim.x + threadIdx.x;
    int stride = gridDim.x * blockDim.x;
    int nv     = B >> 1;  // sample pairs (B even)

    for (int v = tid; v < nv; v += stride) {
        // ---- all loads clustered: 13 VMEM ops in flight ----
        float4 pg  = pred_gps4[v];
        float2 tla = true_lat2[v];
        float2 tlo = true_lon2[v];
        float4 pt  = pred_time4[v];
        float2 h   = hour2[v];
        float2 mn  = minute2[v];
        float4 L0  = logits4[4 * v + 0];
        float4 L1  = logits4[4 * v + 1];
        float4 L2  = logits4[4 * v + 2];
        float4 L3  = logits4[4 * v + 3];
        int2   kk  = orient2[v];
        float2 pa  = pred_alt2[v];
        float2 al  = alt2[v];

        do_sample(pg.x, pg.y, tla.x, tlo.x, pt.x, pt.y, h.x, mn.x,
                  L0, L1, kk.x, pa.x, al.x, s0, s1, o0, o1, ag, at, ao, aa);
        do_sample(pg.z, pg.w, tla.y, tlo.y, pt.z, pt.w, h.y, mn.y,
                  L2, L3, kk.y, pa.y, al.y, s0, s1, o0, o1, ag, at, ao, aa);
    }

    // ---- wave reduce (64 lanes) ----
    #pragma unroll
    for (int off = 32; off > 0; off >>= 1) {
        ag += __shfl_down(ag, off, 64);
        at += __shfl_down(at, off, 64);
        ao += __shfl_down(ao, off, 64);
        aa += __shfl_down(aa, off, 64);
    }

    __shared__ double sm[4][4];  // [wave][loss]
    int lane = threadIdx.x & 63;
    int wave = threadIdx.x >> 6;
    if (lane == 0) {
        sm[wave][0] = (double)ag;
        sm[wave][1] = (double)at;
        sm[wave][2] = (double)ao;
        sm[wave][3] = (double)aa;
    }
    __syncthreads();
    if (threadIdx.x < 4) {
        double s = sm[0][threadIdx.x] + sm[1][threadIdx.x] +
                   sm[2][threadIdx.x] + sm[3][threadIdx.x];
        partials[threadIdx.x * gridDim.x + blockIdx.x] = s;
    }
}

__global__ void __launch_bounds__(256) mtl_final(
    const double* __restrict__ partials,  // [4][GRID]
    float* __restrict__ out, int G, int B)
{
    int t = threadIdx.x;
    double v[4];
    #pragma unroll
    for (int k = 0; k < 4; ++k) {
        double s = 0.0;
        for (int b = t; b < G; b += 256) s += partials[k * G + b];
        v[k] = s;
    }
    #pragma unroll
    for (int off = 32; off > 0; off >>= 1) {
        #pragma unroll
        for (int k = 0; k < 4; ++k) v[k] += __shfl_down(v[k], off, 64);
    }
    __shared__ double sm[4][4];
    int lane = t & 63, wave = t >> 6;
    if (lane == 0) {
        #pragma unroll
        for (int k = 0; k < 4; ++k) sm[wave][k] = v[k];
    }
    __syncthreads();
    if (t == 0) {
        double g = 0, tm = 0, od = 0, al = 0;
        #pragma unroll
        for (int w = 0; w < 4; ++w) {
            g += sm[w][0]; tm += sm[w][1]; od += sm[w][2]; al += sm[w][3];
        }
        double gps    = g  / (double)B;
        double timeL  = tm / (2.0 * (double)B);
        double orient = od / (double)B;
        double altL   = al / (double)B;
        double total  = gps + 0.5 * timeL + 0.3 * orient + 0.2 * altL;
        out[0] = (float)total;
        out[1] = (float)gps;
        out[2] = (float)timeL;
        out[3] = (float)orient;
        out[4] = (float)altL;
    }
}

extern "C" void kernel_launch(void* const* d_in, const int* in_sizes, int n_in,
                              void* d_out, int out_size, void* d_ws, size_t ws_size,
                              hipStream_t stream) {
    const float4* pred_gps4  = (const float4*)d_in[0];
    const float2* true_lat2  = (const float2*)d_in[1];
    const float2* true_lon2  = (const float2*)d_in[2];
    const float4* pred_time4 = (const float4*)d_in[3];
    const float2* hour2      = (const float2*)d_in[4];
    const float2* minute2    = (const float2*)d_in[5];
    const float4* logits4    = (const float4*)d_in[6];
    const int2*   orient2    = (const int2*)d_in[7];
    const float2* pred_alt2  = (const float2*)d_in[8];
    const float2* alt2       = (const float2*)d_in[9];
    const float*  gps_scale  = (const float*)d_in[10];
    const float*  gps_offset = (const float*)d_in[11];

    int B = in_sizes[1];  // true_lat element count
    double* partials = (double*)d_ws;  // 4*GRID*8 = 64 KiB

    mtl_partials<<<GRID, BLOCK, 0, stream>>>(
        pred_gps4, true_lat2, true_lon2, pred_time4, hour2, minute2,
        logits4, orient2, pred_alt2, alt2, gps_scale, gps_offset,
        partials, B);
    mtl_final<<<1, 256, 0, stream>>>(partials, (float*)d_out, GRID, B);
}